// Round 3
// baseline (456.836 us; speedup 1.0000x reference)
//
#include <hip/hip_runtime.h>
#include <hip/hip_bf16.h>

// CSPNet fused forward, MI355X, MFMA version, round 3.
// One block per graph (G=512, A=24). mfma_f32_16x16x32_bf16 everywhere.
// R3: register-generated PE fragments (no pe LDS) -> 48.2KB LDS -> 3 blocks/CU;
// fast silu (v_rcp); pair-packed bf16 converts (v_perm); tl precomputed in pack.

#define NG 512
#define NA 24
#define HID 128
#define TDIM 256
#define NBB 64
#define TPB 256
#define LFRAGS 208
#define OFF_A 0     // We1 rows 0-127   (hA weights)   32 frags
#define OFF_B 32    // We1 rows 128-255 (hB weights)   32 frags
#define OFF_D 64    // We1 rows 262-321 (pe weights, K=64 permuted) 16 frags
#define OFF_E2 80   // We2                              32 frags
#define OFF_N1 112  // Wn1 (K=256)                      64 frags
#define OFF_N2 176  // Wn2                              32 frags
#define FRAG_BYTES (832ull * 1024ull)        // 832 frags * 512 u16 * 2B
#define TL_BYTES   (512ull * 128ull * 4ull)

typedef __bf16 bf16x8 __attribute__((ext_vector_type(8)));
typedef float  f32x4  __attribute__((ext_vector_type(4)));

// ---- LDS layout (bytes) ----
#define O_HB   0        // h bf16 [24][136]                     6528
#define O_BAUG 6528     // aug B frag buf: 8 ct * 512 u16       8192
#define O_AGG  14720    // agg bf16 [24][136]                   6528
#define O_MID  21248    // mid bf16 [96][136]; also embS(12288)+hscrF(12288); t1 buf  26112
#define O_TL   47360    // tl fp32 [128]                        512
#define O_FRAC 47872    // frac fp32 [24][3]                    288
#define O_LAT6 48160    // lattice fp32 [6]                     24
#define SMEM_BYTES 48192

__device__ __forceinline__ float silu_f(float x) {
    return x * __builtin_amdgcn_rcpf(1.0f + __expf(-x));
}

__device__ __forceinline__ unsigned short cvtbf(float x) {
    __hip_bfloat16 b = __float2bfloat16(x);
    return *reinterpret_cast<unsigned short*>(&b);
}

// pack two floats to two bf16 (round-half-up) in one u32: low16 = a, high16 = b
__device__ __forceinline__ unsigned pk2(float a, float b) {
    unsigned ua = __builtin_bit_cast(unsigned, a) + 0x8000u;
    unsigned ub = __builtin_bit_cast(unsigned, b) + 0x8000u;
    return __builtin_amdgcn_perm(ub, ua, 0x07060302u);
}

__device__ __forceinline__ f32x4 MFMA(bf16x8 a, bf16x8 b, f32x4 c) {
    return __builtin_amdgcn_mfma_f32_16x16x32_bf16(a, b, c, 0, 0, 0);
}

__device__ __forceinline__ bf16x8 gfrag(const unsigned short* ws, int fragIdx, int l) {
    const int4* p = reinterpret_cast<const int4*>(ws + (size_t)fragIdx * 512) + l;
    return __builtin_bit_cast(bf16x8, *p);
}
__device__ __forceinline__ bf16x8 lfrag(const unsigned short* buf, int stride, int row0, int kofs, int l) {
    const int4* p = reinterpret_cast<const int4*>(buf + (row0 + (l & 15)) * stride + kofs + ((l >> 4) << 3));
    return __builtin_bit_cast(bf16x8, *p);
}
__device__ __forceinline__ bf16x8 lfragRaw(const unsigned short* buf, int fragIdx, int l) {
    const int4* p = reinterpret_cast<const int4*>(buf + fragIdx * 512) + l;
    return __builtin_bit_cast(bf16x8, *p);
}
// one-hot aug operand (B-side): k<4: i0local; 4..27: j; 28: const 1; 29-31: 0
__device__ __forceinline__ bf16x8 augfrag(int row, int q) {
    int i0l = row / 24;
    int ja  = row - i0l * 24;
    int k2  = 4 + ja;
    bf16x8 v;
#pragma unroll
    for (int e = 0; e < 8; ++e) {
        int k = q * 8 + e;
        bool one = (k == i0l) || (k == k2) || (k == 28);
        v[e] = one ? (__bf16)1.0f : (__bf16)0.0f;
    }
    return v;
}

#define FMA4(ACC, S, W) { (ACC).x += (S)*(W).x; (ACC).y += (S)*(W).y; \
                          (ACC).z += (S)*(W).z; (ACC).w += (S)*(W).w; }

__device__ __forceinline__ float4 ld4(const float* __restrict__ p) {
    return *reinterpret_cast<const float4*>(p);
}

// ---------------- weight packing (+ tl precompute) kernel ----------------
// frag value: W[ks*32 + q*8 + j][nt*16 + c16] at ws[(w*64 + l)*8 + j]
// PE frags use permuted K layout: k' = g*8+e;
//   g<6: (d=g%3, trig=g/3, f=e); g==6: table; g==7: e<4 table else 0.
__global__ void __launch_bounds__(TPB) pack_weights(
    const float* __restrict__ We1, const float* __restrict__ We2,
    const float* __restrict__ Wn1, const float* __restrict__ Wn2,
    const float* __restrict__ t_in, const float* __restrict__ W_lat,
    unsigned short* __restrict__ ws, float* __restrict__ tlAll, int useTl)
{
    if (blockIdx.x >= 208) {
        if (!useTl) return;
        int b2 = blockIdx.x - 208;
        int gl = threadIdx.x >> 5, lane32 = threadIdx.x & 31;
        int g = b2 * 8 + gl, c0 = lane32 * 4;
        float4 acc = make_float4(0.f, 0.f, 0.f, 0.f);
        const float* tg = t_in + (size_t)g * TDIM;
#pragma unroll 4
        for (int k = 0; k < TDIM; ++k) {
            float tv = tg[k];
            float4 w = ld4(W_lat + (size_t)(144 + k) * HID + c0);
            FMA4(acc, tv, w);
        }
        *reinterpret_cast<float4*>(tlAll + (size_t)g * HID + c0) = acc;
        return;
    }
    int w = blockIdx.x * 4 + (threadIdx.x >> 6);   // 0..831
    int l = threadIdx.x & 63;
    int q = l >> 4, c16 = l & 15;
    int layer = w / LFRAGS, r = w % LFRAGS;
    const float* src; int K4, seg, klim; bool isPE = false;
    if (r < 32)       { seg = 0;   K4 = 4; src = We1 + (size_t)layer*322*128;           klim = 128; }
    else if (r < 64)  { seg = 32;  K4 = 4; src = We1 + (size_t)layer*322*128 + 128*128; klim = 128; }
    else if (r < 80)  { seg = 64;  K4 = 2; src = We1 + (size_t)layer*322*128 + 262*128; klim = 64; isPE = true; }
    else if (r < 112) { seg = 80;  K4 = 4; src = We2 + (size_t)layer*128*128;           klim = 128; }
    else if (r < 176) { seg = 112; K4 = 8; src = Wn1 + (size_t)layer*256*128;           klim = 256; }
    else              { seg = 176; K4 = 4; src = Wn2 + (size_t)layer*128*128;           klim = 128; }
    int rr = r - seg; int nt = rr / K4, ks = rr % K4;
    unsigned short vals[8];
#pragma unroll
    for (int j = 0; j < 8; ++j) {
        int row = ks * 32 + q * 8 + j;
        float v = 0.f;
        if (row < klim) {
            if (isPE) {
                int gI = row >> 3, e = row & 7;
                int d = 0, trig = 0, f = 0; bool valid = true;
                if (gI < 6) { d = gI % 3; trig = gI / 3; f = e; }
                else if (gI == 6) {
                    const int dt[8] = {0,0,1,1,2,2,0,0};
                    const int tt[8] = {0,0,0,0,0,0,1,1};
                    const int ft[8] = {8,9,8,9,8,9,8,9};
                    d = dt[e]; trig = tt[e]; f = ft[e];
                } else {
                    if (e < 4) { const int dt[4] = {1,1,2,2}; const int ft[4] = {8,9,8,9};
                                 d = dt[e]; trig = 1; f = ft[e]; }
                    else valid = false;
                }
                if (valid) v = src[(size_t)(trig * 30 + d * 10 + f) * 128 + nt * 16 + c16];
            } else {
                v = src[(size_t)row * 128 + nt * 16 + c16];
            }
        }
        vals[j] = cvtbf(v);
    }
    unsigned int d0 = (unsigned)vals[0] | ((unsigned)vals[1] << 16);
    unsigned int d1 = (unsigned)vals[2] | ((unsigned)vals[3] << 16);
    unsigned int d2 = (unsigned)vals[4] | ((unsigned)vals[5] << 16);
    unsigned int d3 = (unsigned)vals[6] | ((unsigned)vals[7] << 16);
    int4 o = make_int4((int)d0, (int)d1, (int)d2, (int)d3);
    *reinterpret_cast<int4*>(ws + ((size_t)w * 64 + l) * 8) = o;
}

// ---------------- main fused kernel ----------------
__global__ void __launch_bounds__(TPB, 3) cspnet_mfma(
    const float* __restrict__ t_in, const float* __restrict__ bb_embs,
    const float* __restrict__ frac, const float* __restrict__ so3,
    const float* __restrict__ lattices,
    const float* __restrict__ W_emb, const float* __restrict__ b_emb,
    const float* __restrict__ W_lat, const float* __restrict__ b_lat,
    const float* __restrict__ We1, const float* __restrict__ be1,
    const float* __restrict__ be2, const float* __restrict__ bn1,
    const float* __restrict__ bn2,
    const float* __restrict__ W_coord, const float* __restrict__ W_lattice,
    const float* __restrict__ W_so3,
    const unsigned short* __restrict__ wsU, const float* __restrict__ tlAll,
    int useTl, float* __restrict__ out)
{
    __shared__ __align__(16) char smem[SMEM_BYTES];
    unsigned short* hbU   = (unsigned short*)(smem + O_HB);
    unsigned short* baugU = (unsigned short*)(smem + O_BAUG);
    unsigned short* aggU  = (unsigned short*)(smem + O_AGG);
    unsigned short* midU  = (unsigned short*)(smem + O_MID);
    unsigned short* t1U   = midU;
    float* tlS   = (float*)(smem + O_TL);
    float* fracS = (float*)(smem + O_FRAC);
    float* lat6S = (float*)(smem + O_LAT6);
    float* embS  = (float*)(smem + O_MID);           // prologue scratch [24][128] fp32
    float* hscrF = (float*)(smem + O_MID + 12288);   // prologue/epilogue h fp32 [24][128]

    const int g   = blockIdx.x;
    const int tid = threadIdx.x;
    const int l   = tid & 63;
    const int wv  = tid >> 6;
    const int q   = l >> 4;
    const int c16 = l & 15;
    const int mh  = wv >> 1;
    const float inv24 = 1.0f / 24.0f;
    const f32x4 FZ = {0.f, 0.f, 0.f, 0.f};

    // ---------------- prologue ----------------
    if (tid < NA * 3) {
        int i = tid / 3, d = tid - i * 3;
        fracS[i * 3 + d] = frac[(size_t)(g * NA + i) * 3 + d];
    }
    if (tid < 6) lat6S[tid] = lattices[(size_t)g * 6 + tid];
    // zero Baug pad rows ka=29..31
    for (int v = tid; v < 384; v += TPB) {
        int ct = v / 48, rest = v % 48, cl = rest / 3, jp = 5 + rest % 3;
        baugU[ct * 512 + (48 + cl) * 8 + jp] = 0;
    }
    if (useTl) {
        if (tid < HID) tlS[tid] = tlAll[(size_t)g * HID + tid];
    } else if (tid < HID) {
        float acc = 0.f;
        const float* tg = t_in + (size_t)g * TDIM;
        for (int k = 0; k < TDIM; ++k)
            acc += tg[k] * W_lat[(size_t)(144 + k) * HID + tid];
        tlS[tid] = acc;
    }

    // emb = bb @ W_emb + b_emb -> embS
    {
        const int cg = tid & 31, rg = tid >> 5, c0 = cg * 4;
        float4 acc[3];
        float4 be = ld4(b_emb + c0);
        acc[0] = be; acc[1] = be; acc[2] = be;
        const float* bbg = bb_embs + (size_t)(g * NA) * NBB;
#pragma unroll 4
        for (int k = 0; k < NBB; ++k) {
            float4 w = ld4(W_emb + (size_t)k * HID + c0);
            float b0v = bbg[rg * NBB + k];
            float b1v = bbg[(rg + 8) * NBB + k];
            float b2v = bbg[(rg + 16) * NBB + k];
            FMA4(acc[0], b0v, w); FMA4(acc[1], b1v, w); FMA4(acc[2], b2v, w);
        }
#pragma unroll
        for (int s = 0; s < 3; ++s)
            *reinterpret_cast<float4*>(&embS[(rg + 8 * s) * HID + c0]) = acc[s];
    }
    __syncthreads();

    // h = [emb | so3] @ W_lat[0:144] + tl + b_lat -> hscrF (fp32) + hbU (bf16)
    {
        const int cg = tid & 31, rg = tid >> 5, c0 = cg * 4;
        float4 acc[3];
        float4 bl = ld4(b_lat + c0);
        float4 tv = *reinterpret_cast<const float4*>(tlS + c0);
        bl.x += tv.x; bl.y += tv.y; bl.z += tv.z; bl.w += tv.w;
        acc[0] = bl; acc[1] = bl; acc[2] = bl;
#pragma unroll 4
        for (int k = 0; k < HID; ++k) {
            float4 w = ld4(W_lat + (size_t)k * HID + c0);
            float e0 = embS[rg * HID + k], e1 = embS[(rg + 8) * HID + k], e2 = embS[(rg + 16) * HID + k];
            FMA4(acc[0], e0, w); FMA4(acc[1], e1, w); FMA4(acc[2], e2, w);
        }
        const float* so3g = so3 + (size_t)(g * NA) * 16;
#pragma unroll
        for (int k = 0; k < 16; ++k) {
            float4 w = ld4(W_lat + (size_t)(HID + k) * HID + c0);
            float s0 = so3g[rg * 16 + k], s1 = so3g[(rg + 8) * 16 + k], s2 = so3g[(rg + 16) * 16 + k];
            FMA4(acc[0], s0, w); FMA4(acc[1], s1, w); FMA4(acc[2], s2, w);
        }
#pragma unroll
        for (int s = 0; s < 3; ++s) {
            int row = rg + 8 * s;
            *reinterpret_cast<float4*>(&hscrF[row * HID + c0]) = acc[s];
            uint2 pv = make_uint2(pk2(acc[s].x, acc[s].y), pk2(acc[s].z, acc[s].w));
            *reinterpret_cast<uint2*>(&hbU[row * 136 + c0]) = pv;
        }
    }
    __syncthreads();

    // persistent fp32 h in registers (tile map: ct = wv*2+ctl, rt, reg)
    float hreg[2][2][4];
#pragma unroll
    for (int ctl = 0; ctl < 2; ++ctl)
#pragma unroll
        for (int rt = 0; rt < 2; ++rt) {
            int row = rt * 16 + c16;
#pragma unroll
            for (int r = 0; r < 4; ++r)
                hreg[ctl][rt][r] = (row < 24) ? hscrF[row * HID + (wv * 2 + ctl) * 16 + q * 4 + r] : 0.f;
        }
    __syncthreads();

    // chunk/layer-invariant aug one-hot B operands
    bf16x8 augB[3];
#pragma unroll
    for (int rtl = 0; rtl < 3; ++rtl)
        augB[rtl] = augfrag((mh * 3 + rtl) * 16 + c16, q);

    // ---------------- layers ----------------
    for (int ly = 0; ly < 4; ++ly) {
        const int LOFF = ly * LFRAGS;
        const float* be1_l = be1 + ly * HID;
        const float* We1_l = We1 + (size_t)ly * 322 * HID;
        const float* be2_l = be2 + ly * HID;
        const float* bn1_l = bn1 + ly * HID;
        const float* bn2_l = bn2 + ly * HID;

        bf16x8 w1dr[4][2];
#pragma unroll
        for (int ctl = 0; ctl < 4; ++ctl)
#pragma unroll
            for (int ks = 0; ks < 2; ++ks)
                w1dr[ctl][ks] = gfrag(wsU, LOFF + OFF_D + ((wv & 1) * 4 + ctl) * 2 + ks, l);
        bf16x8 we2r[4][4];
#pragma unroll
        for (int ntl = 0; ntl < 4; ++ntl)
#pragma unroll
            for (int ks = 0; ks < 4; ++ks)
                we2r[ntl][ks] = gfrag(wsU, LOFF + OFF_E2 + ((wv & 1) * 4 + ntl) * 4 + ks, l);
        float be2r[4];
#pragma unroll
        for (int ntl = 0; ntl < 4; ++ntl)
            be2r[ntl] = be2_l[((wv & 1) * 4 + ntl) * 16 + c16];

        // P1: hB = h @ We1[128:256] (transposed) -> Baug rows ka=4+j
        {
            f32x4 pacc[2][2];
#pragma unroll
            for (int a = 0; a < 2; ++a) { pacc[a][0] = FZ; pacc[a][1] = FZ; }
#pragma unroll
            for (int ks = 0; ks < 4; ++ks) {
                bf16x8 b0 = lfrag(hbU, 136, 0, ks * 32, l);
                bf16x8 b1 = lfrag(hbU, 136, 16, ks * 32, l);
#pragma unroll
                for (int ctl = 0; ctl < 2; ++ctl) {
                    bf16x8 a = gfrag(wsU, LOFF + OFF_B + (wv * 2 + ctl) * 4 + ks, l);
                    pacc[ctl][0] = MFMA(a, b0, pacc[ctl][0]);
                    pacc[ctl][1] = MFMA(a, b1, pacc[ctl][1]);
                }
            }
#pragma unroll
            for (int ctl = 0; ctl < 2; ++ctl)
#pragma unroll
                for (int rt = 0; rt < 2; ++rt) {
                    int row = rt * 16 + c16;
                    if (row < 24) {
                        int ka = 4 + row, qp = ka >> 3, jp = ka & 7;
#pragma unroll
                        for (int r = 0; r < 4; ++r) {
                            int c = (wv * 2 + ctl) * 16 + q * 4 + r;
                            baugU[(c >> 4) * 512 + (qp * 16 + (c & 15)) * 8 + jp] = cvtbf(pacc[ctl][rt][r]);
                        }
                    }
                }
        }
        // latc -> Baug row ka=28
        if (tid < HID) {
            float a = be1_l[tid];
#pragma unroll
            for (int k = 0; k < 6; ++k)
                a += lat6S[k] * We1_l[(size_t)(256 + k) * HID + tid];
            int c = tid;
            baugU[(c >> 4) * 512 + (48 + (c & 15)) * 8 + 4] = cvtbf(a);
        }
        __syncthreads();   // B_top

        // -------- edge chunks: 6 chunks of 4 source atoms (96 edges) --------
        for (int ck = 0; ck < 6; ++ck) {
            // hA weight frags (issue loads early; overlap with pe-gen)
            bf16x8 oa[2][4];
#pragma unroll
            for (int ctl = 0; ctl < 2; ++ctl)
#pragma unroll
                for (int ks = 0; ks < 4; ++ks)
                    oa[ctl][ks] = gfrag(wsU, LOFF + OFF_A + (wv * 2 + ctl) * 4 + ks, l);

            // register PE fragments (permuted layout), B-operand
            bf16x8 peF[3][2];
#pragma unroll
            for (int rtl = 0; rtl < 3; ++rtl) {
                int r = (mh * 3 + rtl) * 16 + c16;
                int i0l = (r * 43) >> 10;
                int j = r - i0l * 24;
                int i0 = ck * 4 + i0l;
                float fd0 = fracS[j * 3 + 0] - fracS[i0 * 3 + 0];
                float fd1 = fracS[j * 3 + 1] - fracS[i0 * 3 + 1];
                float fd2 = fracS[j * 3 + 2] - fracS[i0 * 3 + 2];
                // ks = 0: g=q -> (d = q%3 with q3->0, trig = q==3)
                {
                    float fsel = (q == 1) ? fd1 : fd0;
                    fsel = (q == 2) ? fd2 : fsel;
                    float toff = (q == 3) ? 0.25f : 0.0f;
                    unsigned p[4];
#pragma unroll
                    for (int ep = 0; ep < 4; ++ep) {
                        float v0 = __builtin_amdgcn_sinf(fsel * (float)(2 * ep) + toff);
                        float v1 = __builtin_amdgcn_sinf(fsel * (float)(2 * ep + 1) + toff);
                        p[ep] = pk2(v0, v1);
                    }
                    peF[rtl][0] = __builtin_bit_cast(bf16x8, make_int4(p[0], p[1], p[2], p[3]));
                }
                // ks = 1: g=4+q. q0:(d1,cos) q1:(d2,cos) q2:g6-table q3:g7-table
                {
                    float fsel = (q == 0) ? fd1 : fd2;
                    unsigned p[4];
#pragma unroll
                    for (int ep = 0; ep < 4; ++ep) {
                        float vv[2];
#pragma unroll
                        for (int hh = 0; hh < 2; ++hh) {
                            int e = 2 * ep + hh;
                            const int   d6[8] = {0,0,1,1,2,2,0,0};
                            const float f6[8] = {8.f,9.f,8.f,9.f,8.f,9.f,8.f,9.f};
                            const float t6[8] = {0,0,0,0,0,0,0.25f,0.25f};
                            float tdef = fsel * (float)e + 0.25f;
                            float fd6 = (d6[e] == 0) ? fd0 : ((d6[e] == 1) ? fd1 : fd2);
                            float t2 = fd6 * f6[e] + t6[e];
                            float t3 = 0.0f;
                            if (e < 4) {
                                const int   d7[4] = {1,1,2,2};
                                const float f7[4] = {8.f,9.f,8.f,9.f};
                                float fd7 = (d7[e] == 1) ? fd1 : fd2;
                                t3 = fd7 * f7[e] + 0.25f;
                            }
                            float t = (q == 2) ? t2 : tdef;
                            t = (q == 3) ? t3 : t;
                            vv[hh] = __builtin_amdgcn_sinf(t);
                        }
                        p[ep] = pk2(vv[0], vv[1]);
                    }
                    peF[rtl][1] = __builtin_bit_cast(bf16x8, make_int4(p[0], p[1], p[2], p[3]));
                }
            }

            // hA slice: hA[ck*4+p] = h @ We1[0:128] -> Baug rows ka=0..3
            {
                f32x4 hacc[2] = {FZ, FZ};
#pragma unroll
                for (int ks = 0; ks < 4; ++ks) {
                    bf16x8 b = lfrag(hbU, 136, ck * 4, ks * 32, l);
#pragma unroll
                    for (int ctl = 0; ctl < 2; ++ctl)
                        hacc[ctl] = MFMA(oa[ctl][ks], b, hacc[ctl]);
                }
                if (c16 < 4) {
#pragma unroll
                    for (int ctl = 0; ctl < 2; ++ctl)
#pragma unroll
                        for (int r = 0; r < 4; ++r) {
                            int c = (wv * 2 + ctl) * 16 + q * 4 + r;
                            baugU[(c >> 4) * 512 + (c & 15) * 8 + c16] = cvtbf(hacc[ctl][r]);
                        }
                }
            }
            __syncthreads();   // B_a

            // mid = silu(pe@W1d + aug) (transposed): wave = (ct-half, rt-third)
            {
                const int ct0 = (wv & 1) * 4;
                f32x4 macc[4][3];
#pragma unroll
                for (int a = 0; a < 4; ++a)
#pragma unroll
                    for (int b = 0; b < 3; ++b) macc[a][b] = FZ;
#pragma unroll
                for (int ks = 0; ks < 2; ++ks)
#pragma unroll
                    for (int ctl = 0; ctl < 4; ++ctl)
#pragma unroll
                        for (int rtl = 0; rtl < 3; ++rtl)
                            macc[ctl][rtl] = MFMA(w1dr[ctl][ks], peF[rtl][ks], macc[ctl][rtl]);
#pragma unroll
                for (int ctl = 0; ctl < 4; ++ctl) {
                    bf16x8 a2 = lfragRaw(baugU, ct0 + ctl, l);
#pragma unroll
                    for (int rtl = 0; rtl < 3; ++rtl)
                        macc[ctl][rtl] = MFMA(a2, augB[rtl], macc[ctl][rtl]);
                }
#pragma unroll
                for (int ctl = 0; ctl < 4; ++ctl)
#pragma unroll
                    for (int rtl = 0; rtl < 3; ++rtl) {
                        int row = (mh * 3 + rtl) * 16 + c16;
                        int cb = (ct0 + ctl) * 16 + q * 4;
                        uint2 pv = make_uint2(pk2(silu_f(macc[ctl][rtl][0]), silu_f(macc[ctl][rtl][1])),
                                              pk2(silu_f(macc[ctl][rtl][2]), silu_f(macc[ctl][rtl][3])));
                        *reinterpret_cast<uint2*>(&midU[row * 136 + cb]) = pv;
                    }
            }
            __syncthreads();   // B_b

            // ef = silu(mid@We2 + be2); agg[i0] = mean_j ef
            {
                f32x4 eacc[3][4];
#pragma unroll
                for (int a = 0; a < 3; ++a)
#pragma unroll
                    for (int b = 0; b < 4; ++b) eacc[a][b] = FZ;
#pragma unroll
                for (int mtl = 0; mtl < 3; ++mtl) {
                    bf16x8 am[4];
#pragma unroll
                    for (int ks = 0; ks < 4; ++ks)
                        am[ks] = lfrag(midU, 136, (3 * mh + mtl) * 16, ks * 32, l);
#pragma unroll
                    for (int ntl = 0; ntl < 4; ++ntl)
#pragma unroll
                        for (int ks = 0; ks < 4; ++ks)
                            eacc[mtl][ntl] = MFMA(am[ks], we2r[ntl][ks], eacc[mtl][ntl]);
                }
#pragma unroll
                for (int ntl = 0; ntl < 4; ++ntl) {
                    float s0 = 0.f, s1 = 0.f;
#pragma unroll
                    for (int r = 0; r < 4; ++r) {
                        float e0 = silu_f(eacc[0][ntl][r] + be2r[ntl]);
                        float e1 = silu_f(eacc[1][ntl][r] + be2r[ntl]);
                        float e2 = silu_f(eacc[2][ntl][r] + be2r[ntl]);
                        s0 += e0; s1 += e2;
                        if (q < 2) s0 += e1; else s1 += e1;
                    }
                    s0 += __shfl_xor(s0, 16, 64); s0 += __shfl_xor(s0, 32, 64);
                    s1 += __shfl_xor(s1, 16, 64); s1 += __shfl_xor(s1, 32, 64);
                    if (q == 0) {
                        int i0a = ck * 4 + 2 * mh;
                        int cc = ((wv & 1) * 4 + ntl) * 16 + c16;
                        aggU[i0a * 136 + cc]       = cvtbf(s0 * inv24);
                        aggU[(i0a + 1) * 136 + cc] = cvtbf(s1 * inv24);
                    }
                }
            }
            __syncthreads();   // B_c
        }

        // -------- node MLP --------
        // t1 = silu([h | agg] @ Wn1 + bn1) (transposed)
        {
            f32x4 t1a[2][2];
#pragma unroll
            for (int a = 0; a < 2; ++a) { t1a[a][0] = FZ; t1a[a][1] = FZ; }
#pragma unroll
            for (int ks = 0; ks < 8; ++ks) {
                bf16x8 b0, b1;
                if (ks < 4) { b0 = lfrag(hbU, 136, 0, ks * 32, l);  b1 = lfrag(hbU, 136, 16, ks * 32, l); }
                else        { b0 = lfrag(aggU, 136, 0, (ks - 4) * 32, l); b1 = lfrag(aggU, 136, 16, (ks - 4) * 32, l); }
#pragma unroll
                for (int ctl = 0; ctl < 2; ++ctl) {
                    bf16x8 a = gfrag(wsU, LOFF + OFF_N1 + (wv * 2 + ctl) * 8 + ks, l);
                    t1a[ctl][0] = MFMA(a, b0, t1a[ctl][0]);
                    t1a[ctl][1] = MFMA(a, b1, t1a[ctl][1]);
                }
            }
            float bn1r[2][4];
#pragma unroll
            for (int ctl = 0; ctl < 2; ++ctl)
#pragma unroll
                for (int r = 0; r < 4; ++r)
                    bn1r[ctl][r] = bn1_l[(wv * 2 + ctl) * 16 + q * 4 + r];
#pragma unroll
            for (int ctl = 0; ctl < 2; ++ctl)
#pragma unroll
                for (int rt = 0; rt < 2; ++rt) {
                    int row = rt * 16 + c16;
                    int cb = (wv * 2 + ctl) * 16 + q * 4;
                    uint2 pv = make_uint2(pk2(silu_f(t1a[ctl][rt][0] + bn1r[ctl][0]),
                                              silu_f(t1a[ctl][rt][1] + bn1r[ctl][1])),
                                          pk2(silu_f(t1a[ctl][rt][2] + bn1r[ctl][2]),
                                              silu_f(t1a[ctl][rt][3] + bn1r[ctl][3])));
                    *reinterpret_cast<uint2*>(&t1U[row * 136 + cb]) = pv;
                }
        }
        __syncthreads();
        // h += silu(t1 @ Wn2 + bn2)
        {
            f32x4 t2a[2][2];
#pragma unroll
            for (int a = 0; a < 2; ++a) { t2a[a][0] = FZ; t2a[a][1] = FZ; }
#pragma unroll
            for (int ks = 0; ks < 4; ++ks) {
                bf16x8 b0 = lfrag(t1U, 136, 0, ks * 32, l);
                bf16x8 b1 = lfrag(t1U, 136, 16, ks * 32, l);
#pragma unroll
                for (int ctl = 0; ctl < 2; ++ctl) {
                    bf16x8 a = gfrag(wsU, LOFF + OFF_N2 + (wv * 2 + ctl) * 4 + ks, l);
                    t2a[ctl][0] = MFMA(a, b0, t2a[ctl][0]);
                    t2a[ctl][1] = MFMA(a, b1, t2a[ctl][1]);
                }
            }
            float bn2r[2][4];
#pragma unroll
            for (int ctl = 0; ctl < 2; ++ctl)
#pragma unroll
                for (int r = 0; r < 4; ++r)
                    bn2r[ctl][r] = bn2_l[(wv * 2 + ctl) * 16 + q * 4 + r];
#pragma unroll
            for (int ctl = 0; ctl < 2; ++ctl)
#pragma unroll
                for (int rt = 0; rt < 2; ++rt) {
                    int row = rt * 16 + c16;
#pragma unroll
                    for (int r = 0; r < 4; ++r)
                        hreg[ctl][rt][r] += silu_f(t2a[ctl][rt][r] + bn2r[ctl][r]);
                    if (row < 24) {
                        int cb = (wv * 2 + ctl) * 16 + q * 4;
                        uint2 pv = make_uint2(pk2(hreg[ctl][rt][0], hreg[ctl][rt][1]),
                                              pk2(hreg[ctl][rt][2], hreg[ctl][rt][3]));
                        *reinterpret_cast<uint2*>(&hbU[row * 136 + cb]) = pv;
                    }
                }
        }
        __syncthreads();
    }

    // ---------------- epilogue ----------------
#pragma unroll
    for (int ctl = 0; ctl < 2; ++ctl)
#pragma unroll
        for (int rt = 0; rt < 2; ++rt) {
            int row = rt * 16 + c16;
            if (row < 24) {
                float4 v = make_float4(hreg[ctl][rt][0], hreg[ctl][rt][1], hreg[ctl][rt][2], hreg[ctl][rt][3]);
                *reinterpret_cast<float4*>(&hscrF[row * HID + (wv * 2 + ctl) * 16 + q * 4]) = v;
            }
        }
    __syncthreads();

    if (tid < HID) {
        float s = 0.f;
#pragma unroll 4
        for (int i = 0; i < NA; ++i) s += hscrF[i * HID + tid];
        tlS[tid] = s * inv24;
    }
    if (tid < NA * 3) {
        int i = tid / 3, d = tid - i * 3;
        float acc = 0.f;
#pragma unroll 4
        for (int k = 0; k < HID; ++k) acc += hscrF[i * HID + k] * W_coord[k * 3 + d];
        acc += fracS[i * 3 + d];
        acc -= floorf(acc);
        out[(size_t)NG * 6 + (size_t)(g * NA + i) * 3 + d] = acc;
    }
    if (tid < NA) {
        int i = tid;
        float v0 = 0.f, v1 = 0.f, v2 = 0.f, v3 = 0.f;
#pragma unroll 4
        for (int k = 0; k < HID; ++k) {
            float hv = hscrF[i * HID + k];
            v0 += hv * W_so3[k * 4 + 0]; v1 += hv * W_so3[k * 4 + 1];
            v2 += hv * W_so3[k * 4 + 2]; v3 += hv * W_so3[k * 4 + 3];
        }
        float inv = 1.0f / sqrtf(v0 * v0 + v1 * v1 + v2 * v2 + v3 * v3);
        size_t o = (size_t)NG * 6 + (size_t)NG * NA * 3 + (size_t)(g * NA + i) * 4;
        out[o + 0] = v0 * inv; out[o + 1] = v1 * inv;
        out[o + 2] = v2 * inv; out[o + 3] = v3 * inv;
    }
    __syncthreads();
    if (tid < 6) {
        float acc = 0.f;
#pragma unroll 4
        for (int c = 0; c < HID; ++c) acc += tlS[c] * W_lattice[c * 6 + tid];
        out[(size_t)g * 6 + tid] = acc;
    }
}

extern "C" void kernel_launch(void* const* d_in, const int* in_sizes, int n_in,
                              void* d_out, int out_size, void* d_ws, size_t ws_size,
                              hipStream_t stream) {
    const float* t_in    = (const float*)d_in[0];
    const float* bb      = (const float*)d_in[1];
    const float* frac    = (const float*)d_in[2];
    const float* so3     = (const float*)d_in[3];
    const float* lat     = (const float*)d_in[4];
    const float* W_emb   = (const float*)d_in[8];
    const float* b_emb   = (const float*)d_in[9];
    const float* W_lat   = (const float*)d_in[10];
    const float* b_lat   = (const float*)d_in[11];
    const float* We1     = (const float*)d_in[12];
    const float* be1     = (const float*)d_in[13];
    const float* We2     = (const float*)d_in[14];
    const float* be2     = (const float*)d_in[15];
    const float* Wn1     = (const float*)d_in[16];
    const float* bn1     = (const float*)d_in[17];
    const float* Wn2     = (const float*)d_in[18];
    const float* bn2     = (const float*)d_in[19];
    const float* W_coord = (const float*)d_in[20];
    const float* W_latt  = (const float*)d_in[21];
    const float* W_so3   = (const float*)d_in[22];

    unsigned short* ws = (unsigned short*)d_ws;
    float* tlAll = (float*)((char*)d_ws + FRAG_BYTES);
    int useTl = (ws_size >= FRAG_BYTES + TL_BYTES) ? 1 : 0;

    hipLaunchKernelGGL(pack_weights, dim3(272), dim3(TPB), 0, stream,
                       We1, We2, Wn1, Wn2, t_in, W_lat, ws, tlAll, useTl);
    hipLaunchKernelGGL(cspnet_mfma, dim3(NG), dim3(TPB), 0, stream,
                       t_in, bb, frac, so3, lat, W_emb, b_emb, W_lat, b_lat,
                       We1, be1, be2, bn1, bn2, W_coord, W_latt, W_so3,
                       (const unsigned short*)ws, (const float*)tlAll, useTl,
                       (float*)d_out);
}

// Round 4
// 317.986 us; speedup vs baseline: 1.4367x; 1.4367x over previous
//
#include <hip/hip_runtime.h>
#include <hip/hip_bf16.h>

// CSPNet fused forward, MI355X, MFMA version, round 4.
// One block per graph (G=512, A=24). mfma_f32_16x16x32_bf16 everywhere.
// R3: register-generated PE fragments (no pe LDS), fast silu (v_rcp),
//     pair-packed bf16 converts (v_perm), tl precomputed in pack kernel.
// R4: launch_bounds back to (256,2) — (256,3) capped unified VGPR/AGPR at
//     ~170 and spilled ~100 regs to scratch (FETCH 17->447MB, WRITE 39->199MB,
//     VALUBusy 60->34). 48.2KB LDS still permits 3 blocks/CU if regs <= 170.

#define NG 512
#define NA 24
#define HID 128
#define TDIM 256
#define NBB 64
#define TPB 256
#define LFRAGS 208
#define OFF_A 0     // We1 rows 0-127   (hA weights)   32 frags
#define OFF_B 32    // We1 rows 128-255 (hB weights)   32 frags
#define OFF_D 64    // We1 rows 262-321 (pe weights, K=64 permuted) 16 frags
#define OFF_E2 80   // We2                              32 frags
#define OFF_N1 112  // Wn1 (K=256)                      64 frags
#define OFF_N2 176  // Wn2                              32 frags
#define FRAG_BYTES (832ull * 1024ull)        // 832 frags * 512 u16 * 2B
#define TL_BYTES   (512ull * 128ull * 4ull)

typedef __bf16 bf16x8 __attribute__((ext_vector_type(8)));
typedef float  f32x4  __attribute__((ext_vector_type(4)));

// ---- LDS layout (bytes) ----
#define O_HB   0        // h bf16 [24][136]                     6528
#define O_BAUG 6528     // aug B frag buf: 8 ct * 512 u16       8192
#define O_AGG  14720    // agg bf16 [24][136]                   6528
#define O_MID  21248    // mid bf16 [96][136]; also embS(12288)+hscrF(12288); t1 buf  26112
#define O_TL   47360    // tl fp32 [128]                        512
#define O_FRAC 47872    // frac fp32 [24][3]                    288
#define O_LAT6 48160    // lattice fp32 [6]                     24
#define SMEM_BYTES 48192

__device__ __forceinline__ float silu_f(float x) {
    return x * __builtin_amdgcn_rcpf(1.0f + __expf(-x));
}

__device__ __forceinline__ unsigned short cvtbf(float x) {
    __hip_bfloat16 b = __float2bfloat16(x);
    return *reinterpret_cast<unsigned short*>(&b);
}

// pack two floats to two bf16 (round-half-up) in one u32: low16 = a, high16 = b
__device__ __forceinline__ unsigned pk2(float a, float b) {
    unsigned ua = __builtin_bit_cast(unsigned, a) + 0x8000u;
    unsigned ub = __builtin_bit_cast(unsigned, b) + 0x8000u;
    return __builtin_amdgcn_perm(ub, ua, 0x07060302u);
}

__device__ __forceinline__ f32x4 MFMA(bf16x8 a, bf16x8 b, f32x4 c) {
    return __builtin_amdgcn_mfma_f32_16x16x32_bf16(a, b, c, 0, 0, 0);
}

__device__ __forceinline__ bf16x8 gfrag(const unsigned short* ws, int fragIdx, int l) {
    const int4* p = reinterpret_cast<const int4*>(ws + (size_t)fragIdx * 512) + l;
    return __builtin_bit_cast(bf16x8, *p);
}
__device__ __forceinline__ bf16x8 lfrag(const unsigned short* buf, int stride, int row0, int kofs, int l) {
    const int4* p = reinterpret_cast<const int4*>(buf + (row0 + (l & 15)) * stride + kofs + ((l >> 4) << 3));
    return __builtin_bit_cast(bf16x8, *p);
}
__device__ __forceinline__ bf16x8 lfragRaw(const unsigned short* buf, int fragIdx, int l) {
    const int4* p = reinterpret_cast<const int4*>(buf + fragIdx * 512) + l;
    return __builtin_bit_cast(bf16x8, *p);
}
// one-hot aug operand (B-side): k<4: i0local; 4..27: j; 28: const 1; 29-31: 0
__device__ __forceinline__ bf16x8 augfrag(int row, int q) {
    int i0l = row / 24;
    int ja  = row - i0l * 24;
    int k2  = 4 + ja;
    bf16x8 v;
#pragma unroll
    for (int e = 0; e < 8; ++e) {
        int k = q * 8 + e;
        bool one = (k == i0l) || (k == k2) || (k == 28);
        v[e] = one ? (__bf16)1.0f : (__bf16)0.0f;
    }
    return v;
}

#define FMA4(ACC, S, W) { (ACC).x += (S)*(W).x; (ACC).y += (S)*(W).y; \
                          (ACC).z += (S)*(W).z; (ACC).w += (S)*(W).w; }

__device__ __forceinline__ float4 ld4(const float* __restrict__ p) {
    return *reinterpret_cast<const float4*>(p);
}

// ---------------- weight packing (+ tl precompute) kernel ----------------
// frag value: W[ks*32 + q*8 + j][nt*16 + c16] at ws[(w*64 + l)*8 + j]
// PE frags use permuted K layout: k' = g*8+e;
//   g<6: (d=g%3, trig=g/3, f=e); g==6: table; g==7: e<4 table else 0.
__global__ void __launch_bounds__(TPB) pack_weights(
    const float* __restrict__ We1, const float* __restrict__ We2,
    const float* __restrict__ Wn1, const float* __restrict__ Wn2,
    const float* __restrict__ t_in, const float* __restrict__ W_lat,
    unsigned short* __restrict__ ws, float* __restrict__ tlAll, int useTl)
{
    if (blockIdx.x >= 208) {
        if (!useTl) return;
        int b2 = blockIdx.x - 208;
        int gl = threadIdx.x >> 5, lane32 = threadIdx.x & 31;
        int g = b2 * 8 + gl, c0 = lane32 * 4;
        float4 acc = make_float4(0.f, 0.f, 0.f, 0.f);
        const float* tg = t_in + (size_t)g * TDIM;
#pragma unroll 4
        for (int k = 0; k < TDIM; ++k) {
            float tv = tg[k];
            float4 w = ld4(W_lat + (size_t)(144 + k) * HID + c0);
            FMA4(acc, tv, w);
        }
        *reinterpret_cast<float4*>(tlAll + (size_t)g * HID + c0) = acc;
        return;
    }
    int w = blockIdx.x * 4 + (threadIdx.x >> 6);   // 0..831
    int l = threadIdx.x & 63;
    int q = l >> 4, c16 = l & 15;
    int layer = w / LFRAGS, r = w % LFRAGS;
    const float* src; int K4, seg, klim; bool isPE = false;
    if (r < 32)       { seg = 0;   K4 = 4; src = We1 + (size_t)layer*322*128;           klim = 128; }
    else if (r < 64)  { seg = 32;  K4 = 4; src = We1 + (size_t)layer*322*128 + 128*128; klim = 128; }
    else if (r < 80)  { seg = 64;  K4 = 2; src = We1 + (size_t)layer*322*128 + 262*128; klim = 64; isPE = true; }
    else if (r < 112) { seg = 80;  K4 = 4; src = We2 + (size_t)layer*128*128;           klim = 128; }
    else if (r < 176) { seg = 112; K4 = 8; src = Wn1 + (size_t)layer*256*128;           klim = 256; }
    else              { seg = 176; K4 = 4; src = Wn2 + (size_t)layer*128*128;           klim = 128; }
    int rr = r - seg; int nt = rr / K4, ks = rr % K4;
    unsigned short vals[8];
#pragma unroll
    for (int j = 0; j < 8; ++j) {
        int row = ks * 32 + q * 8 + j;
        float v = 0.f;
        if (row < klim) {
            if (isPE) {
                int gI = row >> 3, e = row & 7;
                int d = 0, trig = 0, f = 0; bool valid = true;
                if (gI < 6) { d = gI % 3; trig = gI / 3; f = e; }
                else if (gI == 6) {
                    const int dt[8] = {0,0,1,1,2,2,0,0};
                    const int tt[8] = {0,0,0,0,0,0,1,1};
                    const int ft[8] = {8,9,8,9,8,9,8,9};
                    d = dt[e]; trig = tt[e]; f = ft[e];
                } else {
                    if (e < 4) { const int dt[4] = {1,1,2,2}; const int ft[4] = {8,9,8,9};
                                 d = dt[e]; trig = 1; f = ft[e]; }
                    else valid = false;
                }
                if (valid) v = src[(size_t)(trig * 30 + d * 10 + f) * 128 + nt * 16 + c16];
            } else {
                v = src[(size_t)row * 128 + nt * 16 + c16];
            }
        }
        vals[j] = cvtbf(v);
    }
    unsigned int d0 = (unsigned)vals[0] | ((unsigned)vals[1] << 16);
    unsigned int d1 = (unsigned)vals[2] | ((unsigned)vals[3] << 16);
    unsigned int d2 = (unsigned)vals[4] | ((unsigned)vals[5] << 16);
    unsigned int d3 = (unsigned)vals[6] | ((unsigned)vals[7] << 16);
    int4 o = make_int4((int)d0, (int)d1, (int)d2, (int)d3);
    *reinterpret_cast<int4*>(ws + ((size_t)w * 64 + l) * 8) = o;
}

// ---------------- main fused kernel ----------------
__global__ void __launch_bounds__(TPB, 2) cspnet_mfma(
    const float* __restrict__ t_in, const float* __restrict__ bb_embs,
    const float* __restrict__ frac, const float* __restrict__ so3,
    const float* __restrict__ lattices,
    const float* __restrict__ W_emb, const float* __restrict__ b_emb,
    const float* __restrict__ W_lat, const float* __restrict__ b_lat,
    const float* __restrict__ We1, const float* __restrict__ be1,
    const float* __restrict__ be2, const float* __restrict__ bn1,
    const float* __restrict__ bn2,
    const float* __restrict__ W_coord, const float* __restrict__ W_lattice,
    const float* __restrict__ W_so3,
    const unsigned short* __restrict__ wsU, const float* __restrict__ tlAll,
    int useTl, float* __restrict__ out)
{
    __shared__ __align__(16) char smem[SMEM_BYTES];
    unsigned short* hbU   = (unsigned short*)(smem + O_HB);
    unsigned short* baugU = (unsigned short*)(smem + O_BAUG);
    unsigned short* aggU  = (unsigned short*)(smem + O_AGG);
    unsigned short* midU  = (unsigned short*)(smem + O_MID);
    unsigned short* t1U   = midU;
    float* tlS   = (float*)(smem + O_TL);
    float* fracS = (float*)(smem + O_FRAC);
    float* lat6S = (float*)(smem + O_LAT6);
    float* embS  = (float*)(smem + O_MID);           // prologue scratch [24][128] fp32
    float* hscrF = (float*)(smem + O_MID + 12288);   // prologue/epilogue h fp32 [24][128]

    const int g   = blockIdx.x;
    const int tid = threadIdx.x;
    const int l   = tid & 63;
    const int wv  = tid >> 6;
    const int q   = l >> 4;
    const int c16 = l & 15;
    const int mh  = wv >> 1;
    const float inv24 = 1.0f / 24.0f;
    const f32x4 FZ = {0.f, 0.f, 0.f, 0.f};

    // ---------------- prologue ----------------
    if (tid < NA * 3) {
        int i = tid / 3, d = tid - i * 3;
        fracS[i * 3 + d] = frac[(size_t)(g * NA + i) * 3 + d];
    }
    if (tid < 6) lat6S[tid] = lattices[(size_t)g * 6 + tid];
    // zero Baug pad rows ka=29..31
    for (int v = tid; v < 384; v += TPB) {
        int ct = v / 48, rest = v % 48, cl = rest / 3, jp = 5 + rest % 3;
        baugU[ct * 512 + (48 + cl) * 8 + jp] = 0;
    }
    if (useTl) {
        if (tid < HID) tlS[tid] = tlAll[(size_t)g * HID + tid];
    } else if (tid < HID) {
        float acc = 0.f;
        const float* tg = t_in + (size_t)g * TDIM;
        for (int k = 0; k < TDIM; ++k)
            acc += tg[k] * W_lat[(size_t)(144 + k) * HID + tid];
        tlS[tid] = acc;
    }

    // emb = bb @ W_emb + b_emb -> embS
    {
        const int cg = tid & 31, rg = tid >> 5, c0 = cg * 4;
        float4 acc[3];
        float4 be = ld4(b_emb + c0);
        acc[0] = be; acc[1] = be; acc[2] = be;
        const float* bbg = bb_embs + (size_t)(g * NA) * NBB;
#pragma unroll 4
        for (int k = 0; k < NBB; ++k) {
            float4 w = ld4(W_emb + (size_t)k * HID + c0);
            float b0v = bbg[rg * NBB + k];
            float b1v = bbg[(rg + 8) * NBB + k];
            float b2v = bbg[(rg + 16) * NBB + k];
            FMA4(acc[0], b0v, w); FMA4(acc[1], b1v, w); FMA4(acc[2], b2v, w);
        }
#pragma unroll
        for (int s = 0; s < 3; ++s)
            *reinterpret_cast<float4*>(&embS[(rg + 8 * s) * HID + c0]) = acc[s];
    }
    __syncthreads();

    // h = [emb | so3] @ W_lat[0:144] + tl + b_lat -> hscrF (fp32) + hbU (bf16)
    {
        const int cg = tid & 31, rg = tid >> 5, c0 = cg * 4;
        float4 acc[3];
        float4 bl = ld4(b_lat + c0);
        float4 tv = *reinterpret_cast<const float4*>(tlS + c0);
        bl.x += tv.x; bl.y += tv.y; bl.z += tv.z; bl.w += tv.w;
        acc[0] = bl; acc[1] = bl; acc[2] = bl;
#pragma unroll 4
        for (int k = 0; k < HID; ++k) {
            float4 w = ld4(W_lat + (size_t)k * HID + c0);
            float e0 = embS[rg * HID + k], e1 = embS[(rg + 8) * HID + k], e2 = embS[(rg + 16) * HID + k];
            FMA4(acc[0], e0, w); FMA4(acc[1], e1, w); FMA4(acc[2], e2, w);
        }
        const float* so3g = so3 + (size_t)(g * NA) * 16;
#pragma unroll
        for (int k = 0; k < 16; ++k) {
            float4 w = ld4(W_lat + (size_t)(HID + k) * HID + c0);
            float s0 = so3g[rg * 16 + k], s1 = so3g[(rg + 8) * 16 + k], s2 = so3g[(rg + 16) * 16 + k];
            FMA4(acc[0], s0, w); FMA4(acc[1], s1, w); FMA4(acc[2], s2, w);
        }
#pragma unroll
        for (int s = 0; s < 3; ++s) {
            int row = rg + 8 * s;
            *reinterpret_cast<float4*>(&hscrF[row * HID + c0]) = acc[s];
            uint2 pv = make_uint2(pk2(acc[s].x, acc[s].y), pk2(acc[s].z, acc[s].w));
            *reinterpret_cast<uint2*>(&hbU[row * 136 + c0]) = pv;
        }
    }
    __syncthreads();

    // persistent fp32 h in registers (tile map: ct = wv*2+ctl, rt, reg)
    float hreg[2][2][4];
#pragma unroll
    for (int ctl = 0; ctl < 2; ++ctl)
#pragma unroll
        for (int rt = 0; rt < 2; ++rt) {
            int row = rt * 16 + c16;
#pragma unroll
            for (int r = 0; r < 4; ++r)
                hreg[ctl][rt][r] = (row < 24) ? hscrF[row * HID + (wv * 2 + ctl) * 16 + q * 4 + r] : 0.f;
        }
    __syncthreads();

    // chunk/layer-invariant aug one-hot B operands
    bf16x8 augB[3];
#pragma unroll
    for (int rtl = 0; rtl < 3; ++rtl)
        augB[rtl] = augfrag((mh * 3 + rtl) * 16 + c16, q);

    // ---------------- layers ----------------
    for (int ly = 0; ly < 4; ++ly) {
        const int LOFF = ly * LFRAGS;
        const float* be1_l = be1 + ly * HID;
        const float* We1_l = We1 + (size_t)ly * 322 * HID;
        const float* be2_l = be2 + ly * HID;
        const float* bn1_l = bn1 + ly * HID;
        const float* bn2_l = bn2 + ly * HID;

        bf16x8 w1dr[4][2];
#pragma unroll
        for (int ctl = 0; ctl < 4; ++ctl)
#pragma unroll
            for (int ks = 0; ks < 2; ++ks)
                w1dr[ctl][ks] = gfrag(wsU, LOFF + OFF_D + ((wv & 1) * 4 + ctl) * 2 + ks, l);
        bf16x8 we2r[4][4];
#pragma unroll
        for (int ntl = 0; ntl < 4; ++ntl)
#pragma unroll
            for (int ks = 0; ks < 4; ++ks)
                we2r[ntl][ks] = gfrag(wsU, LOFF + OFF_E2 + ((wv & 1) * 4 + ntl) * 4 + ks, l);
        float be2r[4];
#pragma unroll
        for (int ntl = 0; ntl < 4; ++ntl)
            be2r[ntl] = be2_l[((wv & 1) * 4 + ntl) * 16 + c16];

        // P1: hB = h @ We1[128:256] (transposed) -> Baug rows ka=4+j
        {
            f32x4 pacc[2][2];
#pragma unroll
            for (int a = 0; a < 2; ++a) { pacc[a][0] = FZ; pacc[a][1] = FZ; }
#pragma unroll
            for (int ks = 0; ks < 4; ++ks) {
                bf16x8 b0 = lfrag(hbU, 136, 0, ks * 32, l);
                bf16x8 b1 = lfrag(hbU, 136, 16, ks * 32, l);
#pragma unroll
                for (int ctl = 0; ctl < 2; ++ctl) {
                    bf16x8 a = gfrag(wsU, LOFF + OFF_B + (wv * 2 + ctl) * 4 + ks, l);
                    pacc[ctl][0] = MFMA(a, b0, pacc[ctl][0]);
                    pacc[ctl][1] = MFMA(a, b1, pacc[ctl][1]);
                }
            }
#pragma unroll
            for (int ctl = 0; ctl < 2; ++ctl)
#pragma unroll
                for (int rt = 0; rt < 2; ++rt) {
                    int row = rt * 16 + c16;
                    if (row < 24) {
                        int ka = 4 + row, qp = ka >> 3, jp = ka & 7;
#pragma unroll
                        for (int r = 0; r < 4; ++r) {
                            int c = (wv * 2 + ctl) * 16 + q * 4 + r;
                            baugU[(c >> 4) * 512 + (qp * 16 + (c & 15)) * 8 + jp] = cvtbf(pacc[ctl][rt][r]);
                        }
                    }
                }
        }
        // latc -> Baug row ka=28
        if (tid < HID) {
            float a = be1_l[tid];
#pragma unroll
            for (int k = 0; k < 6; ++k)
                a += lat6S[k] * We1_l[(size_t)(256 + k) * HID + tid];
            int c = tid;
            baugU[(c >> 4) * 512 + (48 + (c & 15)) * 8 + 4] = cvtbf(a);
        }
        __syncthreads();   // B_top

        // -------- edge chunks: 6 chunks of 4 source atoms (96 edges) --------
        for (int ck = 0; ck < 6; ++ck) {
            // hA weight frags (issue loads early; overlap with pe-gen)
            bf16x8 oa[2][4];
#pragma unroll
            for (int ctl = 0; ctl < 2; ++ctl)
#pragma unroll
                for (int ks = 0; ks < 4; ++ks)
                    oa[ctl][ks] = gfrag(wsU, LOFF + OFF_A + (wv * 2 + ctl) * 4 + ks, l);

            // register PE fragments (permuted layout), B-operand
            bf16x8 peF[3][2];
#pragma unroll
            for (int rtl = 0; rtl < 3; ++rtl) {
                int r = (mh * 3 + rtl) * 16 + c16;
                int i0l = (r * 43) >> 10;
                int j = r - i0l * 24;
                int i0 = ck * 4 + i0l;
                float fd0 = fracS[j * 3 + 0] - fracS[i0 * 3 + 0];
                float fd1 = fracS[j * 3 + 1] - fracS[i0 * 3 + 1];
                float fd2 = fracS[j * 3 + 2] - fracS[i0 * 3 + 2];
                // ks = 0: g=q -> (d = q%3 with q3->0, trig = q==3)
                {
                    float fsel = (q == 1) ? fd1 : fd0;
                    fsel = (q == 2) ? fd2 : fsel;
                    float toff = (q == 3) ? 0.25f : 0.0f;
                    unsigned p[4];
#pragma unroll
                    for (int ep = 0; ep < 4; ++ep) {
                        float v0 = __builtin_amdgcn_sinf(fsel * (float)(2 * ep) + toff);
                        float v1 = __builtin_amdgcn_sinf(fsel * (float)(2 * ep + 1) + toff);
                        p[ep] = pk2(v0, v1);
                    }
                    peF[rtl][0] = __builtin_bit_cast(bf16x8, make_int4(p[0], p[1], p[2], p[3]));
                }
                // ks = 1: g=4+q. q0:(d1,cos) q1:(d2,cos) q2:g6-table q3:g7-table
                {
                    float fsel = (q == 0) ? fd1 : fd2;
                    unsigned p[4];
#pragma unroll
                    for (int ep = 0; ep < 4; ++ep) {
                        float vv[2];
#pragma unroll
                        for (int hh = 0; hh < 2; ++hh) {
                            int e = 2 * ep + hh;
                            const int   d6[8] = {0,0,1,1,2,2,0,0};
                            const float f6[8] = {8.f,9.f,8.f,9.f,8.f,9.f,8.f,9.f};
                            const float t6[8] = {0,0,0,0,0,0,0.25f,0.25f};
                            float tdef = fsel * (float)e + 0.25f;
                            float fd6 = (d6[e] == 0) ? fd0 : ((d6[e] == 1) ? fd1 : fd2);
                            float t2 = fd6 * f6[e] + t6[e];
                            float t3 = 0.0f;
                            if (e < 4) {
                                const int   d7[4] = {1,1,2,2};
                                const float f7[4] = {8.f,9.f,8.f,9.f};
                                float fd7 = (d7[e] == 1) ? fd1 : fd2;
                                t3 = fd7 * f7[e] + 0.25f;
                            }
                            float t = (q == 2) ? t2 : tdef;
                            t = (q == 3) ? t3 : t;
                            vv[hh] = __builtin_amdgcn_sinf(t);
                        }
                        p[ep] = pk2(vv[0], vv[1]);
                    }
                    peF[rtl][1] = __builtin_bit_cast(bf16x8, make_int4(p[0], p[1], p[2], p[3]));
                }
            }

            // hA slice: hA[ck*4+p] = h @ We1[0:128] -> Baug rows ka=0..3
            {
                f32x4 hacc[2] = {FZ, FZ};
#pragma unroll
                for (int ks = 0; ks < 4; ++ks) {
                    bf16x8 b = lfrag(hbU, 136, ck * 4, ks * 32, l);
#pragma unroll
                    for (int ctl = 0; ctl < 2; ++ctl)
                        hacc[ctl] = MFMA(oa[ctl][ks], b, hacc[ctl]);
                }
                if (c16 < 4) {
#pragma unroll
                    for (int ctl = 0; ctl < 2; ++ctl)
#pragma unroll
                        for (int r = 0; r < 4; ++r) {
                            int c = (wv * 2 + ctl) * 16 + q * 4 + r;
                            baugU[(c >> 4) * 512 + (c & 15) * 8 + c16] = cvtbf(hacc[ctl][r]);
                        }
                }
            }
            __syncthreads();   // B_a

            // mid = silu(pe@W1d + aug) (transposed): wave = (ct-half, rt-third)
            {
                const int ct0 = (wv & 1) * 4;
                f32x4 macc[4][3];
#pragma unroll
                for (int a = 0; a < 4; ++a)
#pragma unroll
                    for (int b = 0; b < 3; ++b) macc[a][b] = FZ;
#pragma unroll
                for (int ks = 0; ks < 2; ++ks)
#pragma unroll
                    for (int ctl = 0; ctl < 4; ++ctl)
#pragma unroll
                        for (int rtl = 0; rtl < 3; ++rtl)
                            macc[ctl][rtl] = MFMA(w1dr[ctl][ks], peF[rtl][ks], macc[ctl][rtl]);
#pragma unroll
                for (int ctl = 0; ctl < 4; ++ctl) {
                    bf16x8 a2 = lfragRaw(baugU, ct0 + ctl, l);
#pragma unroll
                    for (int rtl = 0; rtl < 3; ++rtl)
                        macc[ctl][rtl] = MFMA(a2, augB[rtl], macc[ctl][rtl]);
                }
#pragma unroll
                for (int ctl = 0; ctl < 4; ++ctl)
#pragma unroll
                    for (int rtl = 0; rtl < 3; ++rtl) {
                        int row = (mh * 3 + rtl) * 16 + c16;
                        int cb = (ct0 + ctl) * 16 + q * 4;
                        uint2 pv = make_uint2(pk2(silu_f(macc[ctl][rtl][0]), silu_f(macc[ctl][rtl][1])),
                                              pk2(silu_f(macc[ctl][rtl][2]), silu_f(macc[ctl][rtl][3])));
                        *reinterpret_cast<uint2*>(&midU[row * 136 + cb]) = pv;
                    }
            }
            __syncthreads();   // B_b

            // ef = silu(mid@We2 + be2); agg[i0] = mean_j ef
            {
                f32x4 eacc[3][4];
#pragma unroll
                for (int a = 0; a < 3; ++a)
#pragma unroll
                    for (int b = 0; b < 4; ++b) eacc[a][b] = FZ;
#pragma unroll
                for (int mtl = 0; mtl < 3; ++mtl) {
                    bf16x8 am[4];
#pragma unroll
                    for (int ks = 0; ks < 4; ++ks)
                        am[ks] = lfrag(midU, 136, (3 * mh + mtl) * 16, ks * 32, l);
#pragma unroll
                    for (int ntl = 0; ntl < 4; ++ntl)
#pragma unroll
                        for (int ks = 0; ks < 4; ++ks)
                            eacc[mtl][ntl] = MFMA(am[ks], we2r[ntl][ks], eacc[mtl][ntl]);
                }
#pragma unroll
                for (int ntl = 0; ntl < 4; ++ntl) {
                    float s0 = 0.f, s1 = 0.f;
#pragma unroll
                    for (int r = 0; r < 4; ++r) {
                        float e0 = silu_f(eacc[0][ntl][r] + be2r[ntl]);
                        float e1 = silu_f(eacc[1][ntl][r] + be2r[ntl]);
                        float e2 = silu_f(eacc[2][ntl][r] + be2r[ntl]);
                        s0 += e0; s1 += e2;
                        if (q < 2) s0 += e1; else s1 += e1;
                    }
                    s0 += __shfl_xor(s0, 16, 64); s0 += __shfl_xor(s0, 32, 64);
                    s1 += __shfl_xor(s1, 16, 64); s1 += __shfl_xor(s1, 32, 64);
                    if (q == 0) {
                        int i0a = ck * 4 + 2 * mh;
                        int cc = ((wv & 1) * 4 + ntl) * 16 + c16;
                        aggU[i0a * 136 + cc]       = cvtbf(s0 * inv24);
                        aggU[(i0a + 1) * 136 + cc] = cvtbf(s1 * inv24);
                    }
                }
            }
            __syncthreads();   // B_c
        }

        // -------- node MLP --------
        // t1 = silu([h | agg] @ Wn1 + bn1) (transposed)
        {
            f32x4 t1a[2][2];
#pragma unroll
            for (int a = 0; a < 2; ++a) { t1a[a][0] = FZ; t1a[a][1] = FZ; }
#pragma unroll
            for (int ks = 0; ks < 8; ++ks) {
                bf16x8 b0, b1;
                if (ks < 4) { b0 = lfrag(hbU, 136, 0, ks * 32, l);  b1 = lfrag(hbU, 136, 16, ks * 32, l); }
                else        { b0 = lfrag(aggU, 136, 0, (ks - 4) * 32, l); b1 = lfrag(aggU, 136, 16, (ks - 4) * 32, l); }
#pragma unroll
                for (int ctl = 0; ctl < 2; ++ctl) {
                    bf16x8 a = gfrag(wsU, LOFF + OFF_N1 + (wv * 2 + ctl) * 8 + ks, l);
                    t1a[ctl][0] = MFMA(a, b0, t1a[ctl][0]);
                    t1a[ctl][1] = MFMA(a, b1, t1a[ctl][1]);
                }
            }
            float bn1r[2][4];
#pragma unroll
            for (int ctl = 0; ctl < 2; ++ctl)
#pragma unroll
                for (int r = 0; r < 4; ++r)
                    bn1r[ctl][r] = bn1_l[(wv * 2 + ctl) * 16 + q * 4 + r];
#pragma unroll
            for (int ctl = 0; ctl < 2; ++ctl)
#pragma unroll
                for (int rt = 0; rt < 2; ++rt) {
                    int row = rt * 16 + c16;
                    int cb = (wv * 2 + ctl) * 16 + q * 4;
                    uint2 pv = make_uint2(pk2(silu_f(t1a[ctl][rt][0] + bn1r[ctl][0]),
                                              silu_f(t1a[ctl][rt][1] + bn1r[ctl][1])),
                                          pk2(silu_f(t1a[ctl][rt][2] + bn1r[ctl][2]),
                                              silu_f(t1a[ctl][rt][3] + bn1r[ctl][3])));
                    *reinterpret_cast<uint2*>(&t1U[row * 136 + cb]) = pv;
                }
        }
        __syncthreads();
        // h += silu(t1 @ Wn2 + bn2)
        {
            f32x4 t2a[2][2];
#pragma unroll
            for (int a = 0; a < 2; ++a) { t2a[a][0] = FZ; t2a[a][1] = FZ; }
#pragma unroll
            for (int ks = 0; ks < 4; ++ks) {
                bf16x8 b0 = lfrag(t1U, 136, 0, ks * 32, l);
                bf16x8 b1 = lfrag(t1U, 136, 16, ks * 32, l);
#pragma unroll
                for (int ctl = 0; ctl < 2; ++ctl) {
                    bf16x8 a = gfrag(wsU, LOFF + OFF_N2 + (wv * 2 + ctl) * 4 + ks, l);
                    t2a[ctl][0] = MFMA(a, b0, t2a[ctl][0]);
                    t2a[ctl][1] = MFMA(a, b1, t2a[ctl][1]);
                }
            }
            float bn2r[2][4];
#pragma unroll
            for (int ctl = 0; ctl < 2; ++ctl)
#pragma unroll
                for (int r = 0; r < 4; ++r)
                    bn2r[ctl][r] = bn2_l[(wv * 2 + ctl) * 16 + q * 4 + r];
#pragma unroll
            for (int ctl = 0; ctl < 2; ++ctl)
#pragma unroll
                for (int rt = 0; rt < 2; ++rt) {
                    int row = rt * 16 + c16;
#pragma unroll
                    for (int r = 0; r < 4; ++r)
                        hreg[ctl][rt][r] += silu_f(t2a[ctl][rt][r] + bn2r[ctl][r]);
                    if (row < 24) {
                        int cb = (wv * 2 + ctl) * 16 + q * 4;
                        uint2 pv = make_uint2(pk2(hreg[ctl][rt][0], hreg[ctl][rt][1]),
                                              pk2(hreg[ctl][rt][2], hreg[ctl][rt][3]));
                        *reinterpret_cast<uint2*>(&hbU[row * 136 + cb]) = pv;
                    }
                }
        }
        __syncthreads();
    }

    // ---------------- epilogue ----------------
#pragma unroll
    for (int ctl = 0; ctl < 2; ++ctl)
#pragma unroll
        for (int rt = 0; rt < 2; ++rt) {
            int row = rt * 16 + c16;
            if (row < 24) {
                float4 v = make_float4(hreg[ctl][rt][0], hreg[ctl][rt][1], hreg[ctl][rt][2], hreg[ctl][rt][3]);
                *reinterpret_cast<float4*>(&hscrF[row * HID + (wv * 2 + ctl) * 16 + q * 4]) = v;
            }
        }
    __syncthreads();

    if (tid < HID) {
        float s = 0.f;
#pragma unroll 4
        for (int i = 0; i < NA; ++i) s += hscrF[i * HID + tid];
        tlS[tid] = s * inv24;
    }
    if (tid < NA * 3) {
        int i = tid / 3, d = tid - i * 3;
        float acc = 0.f;
#pragma unroll 4
        for (int k = 0; k < HID; ++k) acc += hscrF[i * HID + k] * W_coord[k * 3 + d];
        acc += fracS[i * 3 + d];
        acc -= floorf(acc);
        out[(size_t)NG * 6 + (size_t)(g * NA + i) * 3 + d] = acc;
    }
    if (tid < NA) {
        int i = tid;
        float v0 = 0.f, v1 = 0.f, v2 = 0.f, v3 = 0.f;
#pragma unroll 4
        for (int k = 0; k < HID; ++k) {
            float hv = hscrF[i * HID + k];
            v0 += hv * W_so3[k * 4 + 0]; v1 += hv * W_so3[k * 4 + 1];
            v2 += hv * W_so3[k * 4 + 2]; v3 += hv * W_so3[k * 4 + 3];
        }
        float inv = 1.0f / sqrtf(v0 * v0 + v1 * v1 + v2 * v2 + v3 * v3);
        size_t o = (size_t)NG * 6 + (size_t)NG * NA * 3 + (size_t)(g * NA + i) * 4;
        out[o + 0] = v0 * inv; out[o + 1] = v1 * inv;
        out[o + 2] = v2 * inv; out[o + 3] = v3 * inv;
    }
    __syncthreads();
    if (tid < 6) {
        float acc = 0.f;
#pragma unroll 4
        for (int c = 0; c < HID; ++c) acc += tlS[c] * W_lattice[c * 6 + tid];
        out[(size_t)g * 6 + tid] = acc;
    }
}

extern "C" void kernel_launch(void* const* d_in, const int* in_sizes, int n_in,
                              void* d_out, int out_size, void* d_ws, size_t ws_size,
                              hipStream_t stream) {
    const float* t_in    = (const float*)d_in[0];
    const float* bb      = (const float*)d_in[1];
    const float* frac    = (const float*)d_in[2];
    const float* so3     = (const float*)d_in[3];
    const float* lat     = (const float*)d_in[4];
    const float* W_emb   = (const float*)d_in[8];
    const float* b_emb   = (const float*)d_in[9];
    const float* W_lat   = (const float*)d_in[10];
    const float* b_lat   = (const float*)d_in[11];
    const float* We1     = (const float*)d_in[12];
    const float* be1     = (const float*)d_in[13];
    const float* We2     = (const float*)d_in[14];
    const float* be2     = (const float*)d_in[15];
    const float* Wn1     = (const float*)d_in[16];
    const float* bn1     = (const float*)d_in[17];
    const float* Wn2     = (const float*)d_in[18];
    const float* bn2     = (const float*)d_in[19];
    const float* W_coord = (const float*)d_in[20];
    const float* W_latt  = (const float*)d_in[21];
    const float* W_so3   = (const float*)d_in[22];

    unsigned short* ws = (unsigned short*)d_ws;
    float* tlAll = (float*)((char*)d_ws + FRAG_BYTES);
    int useTl = (ws_size >= FRAG_BYTES + TL_BYTES) ? 1 : 0;

    hipLaunchKernelGGL(pack_weights, dim3(272), dim3(TPB), 0, stream,
                       We1, We2, Wn1, Wn2, t_in, W_lat, ws, tlAll, useTl);
    hipLaunchKernelGGL(cspnet_mfma, dim3(NG), dim3(TPB), 0, stream,
                       t_in, bb, frac, so3, lat, W_emb, b_emb, W_lat, b_lat,
                       We1, be1, be2, bn1, bn2, W_coord, W_latt, W_so3,
                       (const unsigned short*)ws, (const float*)tlAll, useTl,
                       (float*)d_out);
}